// Round 6
// baseline (99.227 us; speedup 1.0000x reference)
//
#include <hip/hip_runtime.h>
#include <hip/hip_bf16.h>

// Problem constants (fixed by the reference).
#define BB 32
#define CC 32
#define PP 4096      // H*W
#define KS 9
#define KK 64        // output channels
#define CK 288       // C*KS

typedef __attribute__((ext_vector_type(8))) short short8;
typedef __attribute__((ext_vector_type(4))) float float4v;

__device__ inline unsigned short f2bf(float f) {
    __hip_bfloat16 h = __float2bfloat16(f);
    return __builtin_bit_cast(unsigned short, h);
}

// ---- prep (merged): blocks [0,128) transpose x -> xt bf16 pixel-major,
//      4 pixels per thread (float4 reads, 64 B row stores);
//      blocks [128,200) swizzle W -> wa bf16 in MFMA A-fragment order.
// A-frag flat: i = ((kc*4 + mt)*64 + lane)*8 + j
//   -> A[m=ko=mt*16+(lane&15)][k'=kc*32+(lane>>4)*8+j], W-elem = w[ko][c*9+kc], c=(lane>>4)*8+j
__global__ __launch_bounds__(256)
void prep_kernel(const float* __restrict__ x, const float* __restrict__ w,
                 unsigned short* __restrict__ xt, unsigned short* __restrict__ wa) {
    const int t = threadIdx.x;
    const int blk = blockIdx.x;
    if (blk < 128) {
        const int b  = blk >> 2;                       // 4 blocks per batch
        const int p4 = (((blk & 3) << 8) + t) << 2;    // 4 consecutive pixels
        const float* xb = x + (size_t)b * CC * PP + p4;
        unsigned int rows[4][16];                      // [pixel j][channel pair]
#pragma unroll
        for (int c = 0; c < CC; c += 2) {
            float4 v0 = *(const float4*)(xb + (size_t)c * PP);
            float4 v1 = *(const float4*)(xb + (size_t)(c + 1) * PP);
            const int cp = c >> 1;
            rows[0][cp] = (unsigned int)f2bf(v0.x) | ((unsigned int)f2bf(v1.x) << 16);
            rows[1][cp] = (unsigned int)f2bf(v0.y) | ((unsigned int)f2bf(v1.y) << 16);
            rows[2][cp] = (unsigned int)f2bf(v0.z) | ((unsigned int)f2bf(v1.z) << 16);
            rows[3][cp] = (unsigned int)f2bf(v0.w) | ((unsigned int)f2bf(v1.w) << 16);
        }
#pragma unroll
        for (int j = 0; j < 4; ++j) {
            uint4* dst = (uint4*)(xt + ((size_t)b * PP + p4 + j) * CC);
            const uint4* s = (const uint4*)rows[j];
#pragma unroll
            for (int u = 0; u < 4; ++u) dst[u] = s[u];
        }
    } else {
        int i = (blk - 128) * 256 + t;
        if (i < KK * CK) {
            int j  = i & 7;
            int l  = (i >> 3) & 63;
            int mt = (i >> 9) & 3;
            int kc = i >> 11;                 // = neighbor k
            int c  = ((l >> 4) << 3) + j;
            int ko = (mt << 4) + (l & 15);
            wa[i] = f2bf(w[ko * CK + c * KS + kc]);
        }
    }
}

// ---- main: LDS-free. Wave = 32 pixels x 64 ko. A = W (fragment-order,
// L1-hot), B = gathered xt rows (16B/lane direct from global).
// Nontemporal out-stores keep the 33.5 MB stream from evicting xt in L2. ----
__global__ __launch_bounds__(256, 4)
void abc_mfma2_kernel(const unsigned short* __restrict__ xt,
                      const unsigned short* __restrict__ wa,
                      const int* __restrict__ idx,
                      float* __restrict__ out) {
    const int t    = threadIdx.x;
    const int l    = t & 63;
    const int w    = t >> 6;
    const int b    = blockIdx.x >> 5;            // 32 tiles of 128 pixels per batch
    const int p0   = ((blockIdx.x & 31) << 7) + (w << 5);   // wave's 32 pixels
    const int lo16 = l & 15;
    const int quad = l >> 4;

    const unsigned short* xtb = xt + (size_t)b * PP * CC;

    // preload all neighbor indices for this lane's two pixels
    int q[2][KS];
#pragma unroll
    for (int nt = 0; nt < 2; ++nt) {
        const int pl = p0 + nt * 16 + lo16;
#pragma unroll
        for (int kc = 0; kc < KS; ++kc) q[nt][kc] = idx[pl * KS + kc];
    }

    float4v acc[8];   // [mt][nt] -> acc[mt*2+nt]
#pragma unroll
    for (int i = 0; i < 8; ++i) acc[i] = (float4v){0.f, 0.f, 0.f, 0.f};

#pragma unroll 3
    for (int kc = 0; kc < KS; ++kc) {
        short8 bf[2];
#pragma unroll
        for (int nt = 0; nt < 2; ++nt)
            bf[nt] = *(const short8*)(xtb + (size_t)q[nt][kc] * CC + (quad << 3));
        const short8* wf = (const short8*)(wa) + (kc * 4) * 64 + l;
#pragma unroll
        for (int mt = 0; mt < 4; ++mt) {
            short8 a = wf[mt * 64];
#pragma unroll
            for (int nt = 0; nt < 2; ++nt)
                acc[mt * 2 + nt] =
                    __builtin_amdgcn_mfma_f32_16x16x32_bf16(a, bf[nt], acc[mt * 2 + nt], 0, 0, 0);
        }
    }

    // D layout: m(ko_sub)=quad*4+r, n(pixel)=lo16. 64B-segment stores, nontemporal.
    float* ob = out + (size_t)b * KK * PP + p0 + lo16;
#pragma unroll
    for (int mt = 0; mt < 4; ++mt) {
        float* om = ob + (size_t)(mt * 16 + quad * 4) * PP;
#pragma unroll
        for (int r = 0; r < 4; ++r)
#pragma unroll
            for (int nt = 0; nt < 2; ++nt)
                __builtin_nontemporal_store(acc[mt * 2 + nt][r],
                                            om + (size_t)r * PP + nt * 16);
    }
}

// ---- fallback (ws too small): round-2 VALU kernel ----
__global__ __launch_bounds__(256)
void abc_valu_kernel(const float* __restrict__ x, const float* __restrict__ w,
                     const int* __restrict__ idx, float* __restrict__ out) {
    __shared__ float xrow[PP];
    const int t = threadIdx.x;
    const int b = blockIdx.x >> 4;
    const int p = ((blockIdx.x & 15) << 8) + t;
    int q[KS];
#pragma unroll
    for (int k = 0; k < KS; ++k) q[k] = idx[p * KS + k];
    float acc[KK];
#pragma unroll
    for (int i = 0; i < KK; ++i) acc[i] = 0.0f;
    const float* xb = x + (size_t)b * CC * PP;
#pragma unroll 1
    for (int c = 0; c < CC; ++c) {
        const float4* src = (const float4*)(xb + (size_t)c * PP);
        float4* dst = (float4*)xrow;
#pragma unroll
        for (int j = 0; j < 4; ++j) dst[j * 256 + t] = src[j * 256 + t];
        __syncthreads();
        float xv[KS];
#pragma unroll
        for (int k = 0; k < KS; ++k) xv[k] = xrow[q[k]];
#pragma unroll
        for (int k = 0; k < KS; ++k) {
            const int col = c * KS + k;
#pragma unroll
            for (int ko = 0; ko < KK; ++ko)
                acc[ko] += xv[k] * w[ko * CK + col];
        }
        __syncthreads();
    }
    float* ob = out + (size_t)b * KK * PP + p;
#pragma unroll
    for (int ko = 0; ko < KK; ++ko)
        ob[(size_t)ko * PP] = acc[ko];
}

extern "C" void kernel_launch(void* const* d_in, const int* in_sizes, int n_in,
                              void* d_out, int out_size, void* d_ws, size_t ws_size,
                              hipStream_t stream) {
    const float* x  = (const float*)d_in[0];
    const float* w  = (const float*)d_in[1];
    const int* idx  = (const int*)d_in[2];
    float* out      = (float*)d_out;

    const size_t xt_bytes = (size_t)BB * PP * CC * 2;    // 8,388,608
    const size_t need     = xt_bytes + (size_t)KK * CK * 2;

    if (ws_size >= need) {
        unsigned short* xt = (unsigned short*)d_ws;
        unsigned short* wa = (unsigned short*)((char*)d_ws + xt_bytes);
        const int wb_blocks = (KK * CK + 255) / 256;     // 72
        prep_kernel<<<128 + wb_blocks, 256, 0, stream>>>(x, w, xt, wa);
        abc_mfma2_kernel<<<BB * (PP / 128), 256, 0, stream>>>(xt, wa, idx, out);
    } else {
        abc_valu_kernel<<<BB * (PP / 256), 256, 0, stream>>>(x, w, idx, out);
    }
}

// Round 7
// 93.944 us; speedup vs baseline: 1.0562x; 1.0562x over previous
//
#include <hip/hip_runtime.h>
#include <hip/hip_bf16.h>

// Problem constants (fixed by the reference).
#define BB 32
#define CC 32
#define PP 4096      // H*W
#define KS 9
#define KK 64        // output channels
#define CK 288       // C*KS

typedef __attribute__((ext_vector_type(8))) short short8;
typedef __attribute__((ext_vector_type(4))) float float4v;

__device__ inline unsigned short f2bf(float f) {
    __hip_bfloat16 h = __float2bfloat16(f);
    return __builtin_bit_cast(unsigned short, h);
}

// ---- prep (merged): blocks [0,512) transpose x -> xt bf16 pixel-major
//      (1 pixel/thread, coalesced 256B/wave scalar loads, 64B row stores);
//      blocks [512,584) swizzle W -> wa bf16 in MFMA A-fragment order.
// A-frag flat: i = ((kc*4 + mt)*64 + lane)*8 + j
//   -> A[m=ko=mt*16+(lane&15)][k'=kc*32+(lane>>4)*8+j], W-elem = w[ko][c*9+kc], c=(lane>>4)*8+j
__global__ __launch_bounds__(256)
void prep_kernel(const float* __restrict__ x, const float* __restrict__ w,
                 unsigned short* __restrict__ xt, unsigned short* __restrict__ wa) {
    const int t = threadIdx.x;
    const int blk = blockIdx.x;
    if (blk < 512) {
        const int b = blk >> 4;
        const int p = ((blk & 15) << 8) + t;
        const float* xb = x + (size_t)b * CC * PP + p;
        unsigned int buf[16];
#pragma unroll
        for (int c2 = 0; c2 < 16; ++c2) {
            float lo = xb[(size_t)(2 * c2) * PP];
            float hi = xb[(size_t)(2 * c2 + 1) * PP];
            buf[c2] = (unsigned int)f2bf(lo) | ((unsigned int)f2bf(hi) << 16);
        }
        uint4* dst = (uint4*)(xt + ((size_t)b * PP + p) * CC);
        const uint4* s = (const uint4*)buf;
#pragma unroll
        for (int j = 0; j < 4; ++j) dst[j] = s[j];
    } else {
        int i = (blk - 512) * 256 + t;
        if (i < KK * CK) {
            int j  = i & 7;
            int l  = (i >> 3) & 63;
            int mt = (i >> 9) & 3;
            int kc = i >> 11;                 // = neighbor k
            int c  = ((l >> 4) << 3) + j;
            int ko = (mt << 4) + (l & 15);
            wa[i] = f2bf(w[ko * CK + c * KS + kc]);
        }
    }
}

// ---- main: LDS-free. Wave = 32 pixels x 64 ko. A = W (fragment-order,
// L1-hot), B = gathered xt rows (16B/lane direct from global).
// XCD swizzle: xcd = blk&7 (round-robin dispatch) -> b = (blk&7)*4 + ((blk>>3)&3),
// so each XCD's gather working set is 4 b-slices ~= 1.2 MB, L2-resident. ----
__global__ __launch_bounds__(256, 4)
void abc_mfma2_kernel(const unsigned short* __restrict__ xt,
                      const unsigned short* __restrict__ wa,
                      const int* __restrict__ idx,
                      float* __restrict__ out) {
    const int t    = threadIdx.x;
    const int l    = t & 63;
    const int w    = t >> 6;
    const int blk  = blockIdx.x;
    const int b    = ((blk & 7) << 2) | ((blk >> 3) & 3);
    const int tile = blk >> 5;                               // 0..31
    const int p0   = (tile << 7) + (w << 5);                 // wave's 32 pixels
    const int lo16 = l & 15;
    const int quad = l >> 4;

    const unsigned short* xtb = xt + (size_t)b * PP * CC;

    // preload all neighbor indices for this lane's two pixels
    int q[2][KS];
#pragma unroll
    for (int nt = 0; nt < 2; ++nt) {
        const int pl = p0 + nt * 16 + lo16;
#pragma unroll
        for (int kc = 0; kc < KS; ++kc) q[nt][kc] = idx[pl * KS + kc];
    }

    float4v acc[8];   // [mt][nt] -> acc[mt*2+nt]
#pragma unroll
    for (int i = 0; i < 8; ++i) acc[i] = (float4v){0.f, 0.f, 0.f, 0.f};

#pragma unroll 3
    for (int kc = 0; kc < KS; ++kc) {
        short8 bf[2];
#pragma unroll
        for (int nt = 0; nt < 2; ++nt)
            bf[nt] = *(const short8*)(xtb + (size_t)q[nt][kc] * CC + (quad << 3));
        const short8* wf = (const short8*)(wa) + (kc * 4) * 64 + l;
#pragma unroll
        for (int mt = 0; mt < 4; ++mt) {
            short8 a = wf[mt * 64];
#pragma unroll
            for (int nt = 0; nt < 2; ++nt)
                acc[mt * 2 + nt] =
                    __builtin_amdgcn_mfma_f32_16x16x32_bf16(a, bf[nt], acc[mt * 2 + nt], 0, 0, 0);
        }
    }

    // D layout: m(ko_sub)=quad*4+r, n(pixel)=lo16. Full-line nontemporal stores.
    float* ob = out + (size_t)b * KK * PP + p0 + lo16;
#pragma unroll
    for (int mt = 0; mt < 4; ++mt) {
        float* om = ob + (size_t)(mt * 16 + quad * 4) * PP;
#pragma unroll
        for (int r = 0; r < 4; ++r)
#pragma unroll
            for (int nt = 0; nt < 2; ++nt)
                __builtin_nontemporal_store(acc[mt * 2 + nt][r],
                                            om + (size_t)r * PP + nt * 16);
    }
}

// ---- fallback (ws too small): round-2 VALU kernel ----
__global__ __launch_bounds__(256)
void abc_valu_kernel(const float* __restrict__ x, const float* __restrict__ w,
                     const int* __restrict__ idx, float* __restrict__ out) {
    __shared__ float xrow[PP];
    const int t = threadIdx.x;
    const int b = blockIdx.x >> 4;
    const int p = ((blockIdx.x & 15) << 8) + t;
    int q[KS];
#pragma unroll
    for (int k = 0; k < KS; ++k) q[k] = idx[p * KS + k];
    float acc[KK];
#pragma unroll
    for (int i = 0; i < KK; ++i) acc[i] = 0.0f;
    const float* xb = x + (size_t)b * CC * PP;
#pragma unroll 1
    for (int c = 0; c < CC; ++c) {
        const float4* src = (const float4*)(xb + (size_t)c * PP);
        float4* dst = (float4*)xrow;
#pragma unroll
        for (int j = 0; j < 4; ++j) dst[j * 256 + t] = src[j * 256 + t];
        __syncthreads();
        float xv[KS];
#pragma unroll
        for (int k = 0; k < KS; ++k) xv[k] = xrow[q[k]];
#pragma unroll
        for (int k = 0; k < KS; ++k) {
            const int col = c * KS + k;
#pragma unroll
            for (int ko = 0; ko < KK; ++ko)
                acc[ko] += xv[k] * w[ko * CK + col];
        }
        __syncthreads();
    }
    float* ob = out + (size_t)b * KK * PP + p;
#pragma unroll
    for (int ko = 0; ko < KK; ++ko)
        ob[(size_t)ko * PP] = acc[ko];
}

extern "C" void kernel_launch(void* const* d_in, const int* in_sizes, int n_in,
                              void* d_out, int out_size, void* d_ws, size_t ws_size,
                              hipStream_t stream) {
    const float* x  = (const float*)d_in[0];
    const float* w  = (const float*)d_in[1];
    const int* idx  = (const int*)d_in[2];
    float* out      = (float*)d_out;

    const size_t xt_bytes = (size_t)BB * PP * CC * 2;    // 8,388,608
    const size_t need     = xt_bytes + (size_t)KK * CK * 2;

    if (ws_size >= need) {
        unsigned short* xt = (unsigned short*)d_ws;
        unsigned short* wa = (unsigned short*)((char*)d_ws + xt_bytes);
        const int wb_blocks = (KK * CK + 255) / 256;     // 72
        prep_kernel<<<512 + wb_blocks, 256, 0, stream>>>(x, w, xt, wa);
        abc_mfma2_kernel<<<BB * (PP / 128), 256, 0, stream>>>(xt, wa, idx, out);
    } else {
        abc_valu_kernel<<<BB * (PP / 256), 256, 0, stream>>>(x, w, idx, out);
    }
}